// Round 3
// baseline (721.267 us; speedup 1.0000x reference)
//
#include <hip/hip_runtime.h>
#include <math.h>

#define N_NODES 80000
#define E_EDGES 1280000
#define IN_DIM  512
#define OUT_DIM 64
#define POS_DIM 8
#define NEG_SLOPE 0.01f

#define NB_BUCKET 313          // ceil(80000/256), bucket = dst >> 8
#define LDS_EDGE_CAP 8192      // mean bucket size 4090, sigma ~64 -> 64-sigma headroom

// ---------------- GEMM: z = h @ W_fc^T  (M=80000, N=64, K=512) ----------------
__global__ __launch_bounds__(256) void gemm_z(const float* __restrict__ h,
                                              const float* __restrict__ W,
                                              float* __restrict__ z) {
    __shared__ float sh[32][68];
    __shared__ float sw[32][68];
    const int t  = threadIdx.x;
    const int tx = t & 15;
    const int ty = t >> 4;
    const int nbase = blockIdx.x * 64;

    float acc[4][4] = {};

    const int ld_row = t >> 3;
    const int ld_k4  = (t & 7) * 4;

    for (int kc = 0; kc < IN_DIM; kc += 32) {
        #pragma unroll
        for (int rp = 0; rp < 2; ++rp) {
            const int n = ld_row + rp * 32;
            const float4 v = *(const float4*)&h[(size_t)(nbase + n) * IN_DIM + kc + ld_k4];
            sh[ld_k4 + 0][n] = v.x; sh[ld_k4 + 1][n] = v.y;
            sh[ld_k4 + 2][n] = v.z; sh[ld_k4 + 3][n] = v.w;
            const float4 w = *(const float4*)&W[(size_t)n * IN_DIM + kc + ld_k4];
            sw[ld_k4 + 0][n] = w.x; sw[ld_k4 + 1][n] = w.y;
            sw[ld_k4 + 2][n] = w.z; sw[ld_k4 + 3][n] = w.w;
        }
        __syncthreads();
        #pragma unroll
        for (int k = 0; k < 32; ++k) {
            const float4 hv = *(const float4*)&sh[k][ty * 4];
            const float4 wv = *(const float4*)&sw[k][tx * 4];
            const float hr[4] = {hv.x, hv.y, hv.z, hv.w};
            const float wr[4] = {wv.x, wv.y, wv.z, wv.w};
            #pragma unroll
            for (int r = 0; r < 4; ++r)
                #pragma unroll
                for (int c = 0; c < 4; ++c)
                    acc[r][c] += hr[r] * wr[c];
        }
        __syncthreads();
    }
    #pragma unroll
    for (int r = 0; r < 4; ++r) {
        float4 o = {acc[r][0], acc[r][1], acc[r][2], acc[r][3]};
        *(float4*)&z[(size_t)(nbase + ty * 4 + r) * OUT_DIM + tx * 4] = o;
    }
}

// ---------------- per-node attention scores ----------------
__global__ __launch_bounds__(256) void attn_scores(const float* __restrict__ z,
                                                   const float* __restrict__ pos,
                                                   const float* __restrict__ Wa,
                                                   float* __restrict__ el,
                                                   float* __restrict__ er) {
    const int n = blockIdx.x * 256 + threadIdx.x;
    if (n >= N_NODES) return;
    const float* zr = &z[(size_t)n * OUT_DIM];
    float a = 0.f, b = 0.f;
    #pragma unroll
    for (int j = 0; j < OUT_DIM; j += 4) {
        const float4 v = *(const float4*)&zr[j];
        a += v.x * Wa[j + 0] + v.y * Wa[j + 1] + v.z * Wa[j + 2] + v.w * Wa[j + 3];
        b += v.x * Wa[OUT_DIM + j + 0] + v.y * Wa[OUT_DIM + j + 1]
           + v.z * Wa[OUT_DIM + j + 2] + v.w * Wa[OUT_DIM + j + 3];
    }
    const float* pr = &pos[(size_t)n * POS_DIM];
    #pragma unroll
    for (int p = 0; p < POS_DIM; ++p) {
        a += pr[p] * Wa[2 * OUT_DIM + p];
        b += pr[p] * Wa[2 * OUT_DIM + POS_DIM + p];
    }
    el[n] = a;
    er[n] = b;
}

// ---------------- bucket histogram (LDS pre-aggregated) ----------------
// 320 blocks x 256 threads, 4096 edges/block via int4 loads.
__global__ __launch_bounds__(256) void bucket_hist(const int* __restrict__ dst,
                                                   int* __restrict__ bcnt) {
    __shared__ int hh[NB_BUCKET + 7];
    const int t = threadIdx.x;
    for (int i = t; i < NB_BUCKET; i += 256) hh[i] = 0;
    __syncthreads();
    const int e0 = blockIdx.x * 4096 + t * 4;
    #pragma unroll
    for (int rp = 0; rp < 4; ++rp) {
        const int e = e0 + rp * 1024;
        if (e + 3 < E_EDGES) {
            const int4 d4 = *(const int4*)&dst[e];
            atomicAdd(&hh[d4.x >> 8], 1);
            atomicAdd(&hh[d4.y >> 8], 1);
            atomicAdd(&hh[d4.z >> 8], 1);
            atomicAdd(&hh[d4.w >> 8], 1);
        } else {
            for (int j = 0; j < 4; ++j)
                if (e + j < E_EDGES) atomicAdd(&hh[dst[e + j] >> 8], 1);
        }
    }
    __syncthreads();
    for (int i = t; i < NB_BUCKET; i += 256) {
        const int c = hh[i];
        if (c) atomicAdd(&bcnt[i], c);
    }
}

// ---------------- scan 313 bucket counts, one wave ----------------
__global__ __launch_bounds__(64) void bucket_scan(const int* __restrict__ bcnt,
                                                  int* __restrict__ bstart,
                                                  int* __restrict__ bcur) {
    const int t = threadIdx.x;  // lane 0..63, 5 elems each (covers 320)
    int c[5];
    int s = 0;
    #pragma unroll
    for (int j = 0; j < 5; ++j) {
        const int i = t * 5 + j;
        c[j] = (i < NB_BUCKET) ? bcnt[i] : 0;
        s += c[j];
    }
    int ps = s;
    #pragma unroll
    for (int off = 1; off < 64; off <<= 1) {
        const int u = __shfl_up(ps, off);
        if (t >= off) ps += u;
    }
    int run = ps - s;  // exclusive prefix of this lane's chunk
    #pragma unroll
    for (int j = 0; j < 5; ++j) {
        const int i = t * 5 + j;
        if (i < NB_BUCKET) {
            bstart[i] = run;
            bcur[i]   = run;
            run += c[j];
        }
    }
    if (t == 63) bstart[NB_BUCKET] = E_EDGES;
}

// ---------------- pass 1: scatter edges into bucket regions (packed) ----------------
__global__ __launch_bounds__(256) void bucket_scatter(const int* __restrict__ src,
                                                      const int* __restrict__ dst,
                                                      int* __restrict__ bcur,
                                                      int* __restrict__ ebuf) {
    const int e = blockIdx.x * 256 + threadIdx.x;
    if (e >= E_EDGES) return;
    const int d = dst[e];
    const int key = (src[e] << 8) | (d & 255);
    const int p = atomicAdd(&bcur[d >> 8], 1);
    ebuf[p] = key;
}

// ---------------- pass 2: per-bucket CSR build, in place ----------------
// One block per bucket. Stages the bucket's packed edges in LDS, counts per-node,
// block-scans, writes offs, then scatters src back over the same global region.
__global__ __launch_bounds__(256) void bucket_csr(int* __restrict__ ebuf,
                                                  const int* __restrict__ bstart,
                                                  int* __restrict__ offs) {
    __shared__ int se[LDS_EDGE_CAP];
    __shared__ int cnt[256];
    __shared__ int cur[256];
    __shared__ int wt[4];
    const int b = blockIdx.x;
    const int t = threadIdx.x;
    const int lane = t & 63;
    const int w = t >> 6;
    const int lo = bstart[b];
    const int ne = bstart[b + 1] - lo;

    cnt[t] = 0;
    __syncthreads();

    // stage + count (overflow beyond LDS cap held in registers; practically never)
    int ovf[8];
    int novf = 0;
    for (int i = t; i < ne; i += 256) {
        const int k = ebuf[lo + i];
        atomicAdd(&cnt[k & 255], 1);
        if (i < LDS_EDGE_CAP) se[i] = k;
        else if (novf < 8) ovf[novf++] = k;
    }
    __syncthreads();

    // block-exclusive scan of cnt -> cur
    const int v = cnt[t];
    int s = v;
    #pragma unroll
    for (int off = 1; off < 64; off <<= 1) {
        const int u = __shfl_up(s, off);
        if (lane >= off) s += u;
    }
    if (lane == 63) wt[w] = s;
    __syncthreads();
    int base = 0;
    #pragma unroll
    for (int i = 0; i < 4; ++i)
        if (i < w) base += wt[i];
    const int excl = base + s - v;
    cur[t] = excl;
    const int node = b * 256 + t;
    if (node < N_NODES) offs[node] = lo + excl;
    if (b == NB_BUCKET - 1 && t == 0) offs[N_NODES] = E_EDGES;
    __syncthreads();

    // scatter src in place
    const int nst = (ne < LDS_EDGE_CAP) ? ne : LDS_EDGE_CAP;
    for (int i = t; i < nst; i += 256) {
        const int k = se[i];
        const int p = atomicAdd(&cur[k & 255], 1);
        ebuf[lo + p] = k >> 8;
    }
    for (int j = 0; j < novf; ++j) {
        const int k = ovf[j];
        const int p = atomicAdd(&cur[k & 255], 1);
        ebuf[lo + p] = k >> 8;
    }
}

// ---------------- edge softmax + aggregate: one wave per dst node ----------------
__global__ __launch_bounds__(256) void aggregate(const int* __restrict__ offs,
                                                 const int* __restrict__ esrc,
                                                 const float* __restrict__ el,
                                                 const float* __restrict__ er,
                                                 const float* __restrict__ z,
                                                 float* __restrict__ out) {
    const int wave = (int)((blockIdx.x * 256 + threadIdx.x) >> 6);
    const int lane = threadIdx.x & 63;
    if (wave >= N_NODES) return;
    const int d = wave;
    const int start = offs[d];
    const int end   = offs[d + 1];
    const float erd = er[d];

    float m = -INFINITY;
    for (int i = start + lane; i < end; i += 64) {
        const int s = esrc[i];
        float e = el[s] + erd;
        e = e > 0.f ? e : NEG_SLOPE * e;
        m = fmaxf(m, e);
    }
    #pragma unroll
    for (int off = 32; off; off >>= 1) m = fmaxf(m, __shfl_xor(m, off));

    float acc = 0.f;
    float dsum = 0.f;
    for (int base = start; base < end; base += 64) {
        const int cl = min(64, end - base);
        int s_i = 0;
        float ex_i = 0.f;
        if (lane < cl) {
            s_i = esrc[base + lane];
            float e = el[s_i] + erd;
            e = e > 0.f ? e : NEG_SLOPE * e;
            ex_i = __expf(e - m);
        }
        dsum += ex_i;
        for (int bb = 0; bb < cl; ++bb) {
            const float wgt = __shfl(ex_i, bb);
            const int s   = __shfl(s_i, bb);
            acc += wgt * z[(size_t)s * OUT_DIM + lane];
        }
    }
    #pragma unroll
    for (int off = 32; off; off >>= 1) dsum += __shfl_xor(dsum, off);

    out[(size_t)d * OUT_DIM + lane] = (end > start) ? (acc / dsum) : 0.f;
}

// ---------------- launch ----------------
extern "C" void kernel_launch(void* const* d_in, const int* in_sizes, int n_in,
                              void* d_out, int out_size, void* d_ws, size_t ws_size,
                              hipStream_t stream) {
    const float* h   = (const float*)d_in[0];
    const float* pos = (const float*)d_in[1];
    const int* src   = (const int*)d_in[2];
    const int* dst   = (const int*)d_in[3];
    const float* Wfc = (const float*)d_in[4];
    const float* Wa  = (const float*)d_in[5];
    float* out = (float*)d_out;

    char* ws = (char*)d_ws;
    float* z      = (float*)(ws);               // 20,480,000 B
    float* el     = (float*)(ws + 20480000);    // 320,000 B
    float* er     = (float*)(ws + 20800000);    // 320,000 B
    int*   offs   = (int*)  (ws + 21120000);    // 320,016 B (N+1, padded)
    int*   ebuf   = (int*)  (ws + 21440016);    // 5,120,000 B (packed edges -> CSR src, in place)
    int*   bcnt   = (int*)  (ws + 26560016);    // 1,280 B
    int*   bstart = (int*)  (ws + 26561296);    // 1,280 B
    int*   bcur   = (int*)  (ws + 26562576);    // 1,280 B

    gemm_z<<<N_NODES / 64, 256, 0, stream>>>(h, Wfc, z);
    attn_scores<<<(N_NODES + 255) / 256, 256, 0, stream>>>(z, pos, Wa, el, er);
    hipMemsetAsync(bcnt, 0, NB_BUCKET * sizeof(int), stream);
    bucket_hist<<<320, 256, 0, stream>>>(dst, bcnt);
    bucket_scan<<<1, 64, 0, stream>>>(bcnt, bstart, bcur);
    bucket_scatter<<<E_EDGES / 256, 256, 0, stream>>>(src, dst, bcur, ebuf);
    bucket_csr<<<NB_BUCKET, 256, 0, stream>>>(ebuf, bstart, offs);
    aggregate<<<N_NODES / 4, 256, 0, stream>>>(offs, ebuf, el, er, z, out);
}

// Round 4
// 228.257 us; speedup vs baseline: 3.1599x; 3.1599x over previous
//
#include <hip/hip_runtime.h>
#include <math.h>

#define N_NODES 80000
#define E_EDGES 1280000
#define IN_DIM  512
#define OUT_DIM 64
#define POS_DIM 8
#define NEG_SLOPE 0.01f

#define NB_BUCKET 313          // ceil(80000/256), bucket = dst >> 8
#define LDS_EDGE_CAP 8192      // mean bucket size 4090, sigma ~64
#define SCAT_CHUNK 4096        // edges per scatter block
#define SCAT_NB 313            // ceil(E / 4096)

// ---------------- GEMM: z = h @ W_fc^T  (M=80000, N=64, K=512) ----------------
__global__ __launch_bounds__(256) void gemm_z(const float* __restrict__ h,
                                              const float* __restrict__ W,
                                              float* __restrict__ z) {
    __shared__ float sh[32][68];
    __shared__ float sw[32][68];
    const int t  = threadIdx.x;
    const int tx = t & 15;
    const int ty = t >> 4;
    const int nbase = blockIdx.x * 64;

    float acc[4][4] = {};

    const int ld_row = t >> 3;
    const int ld_k4  = (t & 7) * 4;

    for (int kc = 0; kc < IN_DIM; kc += 32) {
        #pragma unroll
        for (int rp = 0; rp < 2; ++rp) {
            const int n = ld_row + rp * 32;
            const float4 v = *(const float4*)&h[(size_t)(nbase + n) * IN_DIM + kc + ld_k4];
            sh[ld_k4 + 0][n] = v.x; sh[ld_k4 + 1][n] = v.y;
            sh[ld_k4 + 2][n] = v.z; sh[ld_k4 + 3][n] = v.w;
            const float4 w = *(const float4*)&W[(size_t)n * IN_DIM + kc + ld_k4];
            sw[ld_k4 + 0][n] = w.x; sw[ld_k4 + 1][n] = w.y;
            sw[ld_k4 + 2][n] = w.z; sw[ld_k4 + 3][n] = w.w;
        }
        __syncthreads();
        #pragma unroll
        for (int k = 0; k < 32; ++k) {
            const float4 hv = *(const float4*)&sh[k][ty * 4];
            const float4 wv = *(const float4*)&sw[k][tx * 4];
            const float hr[4] = {hv.x, hv.y, hv.z, hv.w};
            const float wr[4] = {wv.x, wv.y, wv.z, wv.w};
            #pragma unroll
            for (int r = 0; r < 4; ++r)
                #pragma unroll
                for (int c = 0; c < 4; ++c)
                    acc[r][c] += hr[r] * wr[c];
        }
        __syncthreads();
    }
    #pragma unroll
    for (int r = 0; r < 4; ++r) {
        float4 o = {acc[r][0], acc[r][1], acc[r][2], acc[r][3]};
        *(float4*)&z[(size_t)(nbase + ty * 4 + r) * OUT_DIM + tx * 4] = o;
    }
}

// ---------------- per-node attention scores ----------------
__global__ __launch_bounds__(256) void attn_scores(const float* __restrict__ z,
                                                   const float* __restrict__ pos,
                                                   const float* __restrict__ Wa,
                                                   float* __restrict__ el,
                                                   float* __restrict__ er) {
    const int n = blockIdx.x * 256 + threadIdx.x;
    if (n >= N_NODES) return;
    const float* zr = &z[(size_t)n * OUT_DIM];
    float a = 0.f, b = 0.f;
    #pragma unroll
    for (int j = 0; j < OUT_DIM; j += 4) {
        const float4 v = *(const float4*)&zr[j];
        a += v.x * Wa[j + 0] + v.y * Wa[j + 1] + v.z * Wa[j + 2] + v.w * Wa[j + 3];
        b += v.x * Wa[OUT_DIM + j + 0] + v.y * Wa[OUT_DIM + j + 1]
           + v.z * Wa[OUT_DIM + j + 2] + v.w * Wa[OUT_DIM + j + 3];
    }
    const float* pr = &pos[(size_t)n * POS_DIM];
    #pragma unroll
    for (int p = 0; p < POS_DIM; ++p) {
        a += pr[p] * Wa[2 * OUT_DIM + p];
        b += pr[p] * Wa[2 * OUT_DIM + POS_DIM + p];
    }
    el[n] = a;
    er[n] = b;
}

// ---------------- bucket histogram (LDS pre-aggregated) ----------------
__global__ __launch_bounds__(256) void bucket_hist(const int* __restrict__ dst,
                                                   int* __restrict__ bcnt) {
    __shared__ int hh[NB_BUCKET + 7];
    const int t = threadIdx.x;
    for (int i = t; i < NB_BUCKET; i += 256) hh[i] = 0;
    __syncthreads();
    const int e0 = blockIdx.x * 4096 + t * 4;
    #pragma unroll
    for (int rp = 0; rp < 4; ++rp) {
        const int e = e0 + rp * 1024;
        if (e + 3 < E_EDGES) {
            const int4 d4 = *(const int4*)&dst[e];
            atomicAdd(&hh[d4.x >> 8], 1);
            atomicAdd(&hh[d4.y >> 8], 1);
            atomicAdd(&hh[d4.z >> 8], 1);
            atomicAdd(&hh[d4.w >> 8], 1);
        } else {
            for (int j = 0; j < 4; ++j)
                if (e + j < E_EDGES) atomicAdd(&hh[dst[e + j] >> 8], 1);
        }
    }
    __syncthreads();
    for (int i = t; i < NB_BUCKET; i += 256) {
        const int c = hh[i];
        if (c) atomicAdd(&bcnt[i], c);
    }
}

// ---------------- scan 313 bucket counts, one wave ----------------
__global__ __launch_bounds__(64) void bucket_scan(const int* __restrict__ bcnt,
                                                  int* __restrict__ bstart,
                                                  int* __restrict__ bcur) {
    const int t = threadIdx.x;
    int c[5];
    int s = 0;
    #pragma unroll
    for (int j = 0; j < 5; ++j) {
        const int i = t * 5 + j;
        c[j] = (i < NB_BUCKET) ? bcnt[i] : 0;
        s += c[j];
    }
    int ps = s;
    #pragma unroll
    for (int off = 1; off < 64; off <<= 1) {
        const int u = __shfl_up(ps, off);
        if (t >= off) ps += u;
    }
    int run = ps - s;
    #pragma unroll
    for (int j = 0; j < 5; ++j) {
        const int i = t * 5 + j;
        if (i < NB_BUCKET) {
            bstart[i] = run;
            bcur[i]   = run;
            run += c[j];
        }
    }
    if (t == 63) bstart[NB_BUCKET] = E_EDGES;
}

// ---------------- pass 1: block-aggregated scatter into bucket regions ----------------
// Each block: LDS histogram of its 4096 edges (LDS atomics give local rank),
// ONE global atomicAdd per touched bucket to reserve a contiguous range,
// then packed writes into the reserved sub-ranges.
__global__ __launch_bounds__(256) void bucket_scatter_agg(const int* __restrict__ src,
                                                          const int* __restrict__ dst,
                                                          int* __restrict__ bcur,
                                                          int* __restrict__ ebuf) {
    __shared__ int hh[NB_BUCKET];
    __shared__ int gb[NB_BUCKET];
    const int t = threadIdx.x;
    const int e0 = blockIdx.x * SCAT_CHUNK;

    for (int i = t; i < NB_BUCKET; i += 256) hh[i] = 0;
    __syncthreads();

    int key[16];
    short bk[16];
    short lr[16];
    #pragma unroll
    for (int r = 0; r < 16; ++r) {
        const int e = e0 + r * 256 + t;
        if (e < E_EDGES) {
            const int d = dst[e];
            const int s = src[e];
            bk[r]  = (short)(d >> 8);
            key[r] = (s << 8) | (d & 255);
            lr[r]  = (short)atomicAdd(&hh[d >> 8], 1);
        } else {
            bk[r] = -1;
        }
    }
    __syncthreads();

    for (int i = t; i < NB_BUCKET; i += 256) {
        const int c = hh[i];
        gb[i] = c ? atomicAdd(&bcur[i], c) : 0;
    }
    __syncthreads();

    #pragma unroll
    for (int r = 0; r < 16; ++r) {
        if (bk[r] >= 0) {
            ebuf[gb[bk[r]] + lr[r]] = key[r];
        }
    }
}

// ---------------- pass 2: per-bucket CSR build, in place ----------------
__global__ __launch_bounds__(256) void bucket_csr(int* __restrict__ ebuf,
                                                  const int* __restrict__ bstart,
                                                  int* __restrict__ offs) {
    __shared__ int se[LDS_EDGE_CAP];
    __shared__ int cnt[256];
    __shared__ int cur[256];
    __shared__ int wt[4];
    const int b = blockIdx.x;
    const int t = threadIdx.x;
    const int lane = t & 63;
    const int w = t >> 6;
    const int lo = bstart[b];
    const int ne = bstart[b + 1] - lo;

    cnt[t] = 0;
    __syncthreads();

    int ovf[8];
    int novf = 0;
    for (int i = t; i < ne; i += 256) {
        const int k = ebuf[lo + i];
        atomicAdd(&cnt[k & 255], 1);
        if (i < LDS_EDGE_CAP) se[i] = k;
        else if (novf < 8) ovf[novf++] = k;
    }
    __syncthreads();

    const int v = cnt[t];
    int s = v;
    #pragma unroll
    for (int off = 1; off < 64; off <<= 1) {
        const int u = __shfl_up(s, off);
        if (lane >= off) s += u;
    }
    if (lane == 63) wt[w] = s;
    __syncthreads();
    int base = 0;
    #pragma unroll
    for (int i = 0; i < 4; ++i)
        if (i < w) base += wt[i];
    const int excl = base + s - v;
    cur[t] = excl;
    const int node = b * 256 + t;
    if (node < N_NODES) offs[node] = lo + excl;
    if (b == NB_BUCKET - 1 && t == 0) offs[N_NODES] = E_EDGES;
    __syncthreads();

    const int nst = (ne < LDS_EDGE_CAP) ? ne : LDS_EDGE_CAP;
    for (int i = t; i < nst; i += 256) {
        const int k = se[i];
        const int p = atomicAdd(&cur[k & 255], 1);
        ebuf[lo + p] = k >> 8;
    }
    for (int j = 0; j < novf; ++j) {
        const int k = ovf[j];
        const int p = atomicAdd(&cur[k & 255], 1);
        ebuf[lo + p] = k >> 8;
    }
}

// ---------------- edge softmax + aggregate: one wave per dst node ----------------
__global__ __launch_bounds__(256) void aggregate(const int* __restrict__ offs,
                                                 const int* __restrict__ esrc,
                                                 const float* __restrict__ el,
                                                 const float* __restrict__ er,
                                                 const float* __restrict__ z,
                                                 float* __restrict__ out) {
    const int wave = (int)((blockIdx.x * 256 + threadIdx.x) >> 6);
    const int lane = threadIdx.x & 63;
    if (wave >= N_NODES) return;
    const int d = wave;
    const int start = offs[d];
    const int end   = offs[d + 1];
    const float erd = er[d];

    float m = -INFINITY;
    for (int i = start + lane; i < end; i += 64) {
        const int s = esrc[i];
        float e = el[s] + erd;
        e = e > 0.f ? e : NEG_SLOPE * e;
        m = fmaxf(m, e);
    }
    #pragma unroll
    for (int off = 32; off; off >>= 1) m = fmaxf(m, __shfl_xor(m, off));

    float acc = 0.f;
    float dsum = 0.f;
    for (int base = start; base < end; base += 64) {
        const int cl = min(64, end - base);
        int s_i = 0;
        float ex_i = 0.f;
        if (lane < cl) {
            s_i = esrc[base + lane];
            float e = el[s_i] + erd;
            e = e > 0.f ? e : NEG_SLOPE * e;
            ex_i = __expf(e - m);
        }
        dsum += ex_i;
        for (int bb = 0; bb < cl; ++bb) {
            const float wgt = __shfl(ex_i, bb);
            const int s   = __shfl(s_i, bb);
            acc += wgt * z[(size_t)s * OUT_DIM + lane];
        }
    }
    #pragma unroll
    for (int off = 32; off; off >>= 1) dsum += __shfl_xor(dsum, off);

    out[(size_t)d * OUT_DIM + lane] = (end > start) ? (acc / dsum) : 0.f;
}

// ---------------- launch ----------------
extern "C" void kernel_launch(void* const* d_in, const int* in_sizes, int n_in,
                              void* d_out, int out_size, void* d_ws, size_t ws_size,
                              hipStream_t stream) {
    const float* h   = (const float*)d_in[0];
    const float* pos = (const float*)d_in[1];
    const int* src   = (const int*)d_in[2];
    const int* dst   = (const int*)d_in[3];
    const float* Wfc = (const float*)d_in[4];
    const float* Wa  = (const float*)d_in[5];
    float* out = (float*)d_out;

    char* ws = (char*)d_ws;
    float* z      = (float*)(ws);               // 20,480,000 B
    float* el     = (float*)(ws + 20480000);    // 320,000 B
    float* er     = (float*)(ws + 20800000);    // 320,000 B
    int*   offs   = (int*)  (ws + 21120000);    // 320,016 B (N+1, padded)
    int*   ebuf   = (int*)  (ws + 21440016);    // 5,120,000 B
    int*   bcnt   = (int*)  (ws + 26560016);    // 1,280 B
    int*   bstart = (int*)  (ws + 26561296);    // 1,280 B
    int*   bcur   = (int*)  (ws + 26562576);    // 1,280 B

    gemm_z<<<N_NODES / 64, 256, 0, stream>>>(h, Wfc, z);
    attn_scores<<<(N_NODES + 255) / 256, 256, 0, stream>>>(z, pos, Wa, el, er);
    hipMemsetAsync(bcnt, 0, NB_BUCKET * sizeof(int), stream);
    bucket_hist<<<320, 256, 0, stream>>>(dst, bcnt);
    bucket_scan<<<1, 64, 0, stream>>>(bcnt, bstart, bcur);
    bucket_scatter_agg<<<SCAT_NB, 256, 0, stream>>>(src, dst, bcur, ebuf);
    bucket_csr<<<NB_BUCKET, 256, 0, stream>>>(ebuf, bstart, offs);
    aggregate<<<N_NODES / 4, 256, 0, stream>>>(offs, ebuf, el, er, z, out);
}

// Round 5
// 177.463 us; speedup vs baseline: 4.0643x; 1.2862x over previous
//
#include <hip/hip_runtime.h>
#include <math.h>

#define N_NODES 80000
#define E_EDGES 1280000
#define IN_DIM  512
#define OUT_DIM 64
#define POS_DIM 8
#define NEG_SLOPE 0.01f

#define NB_BUCKET 313          // ceil(80000/256), bucket = dst >> 8
#define LDS_EDGE_CAP 8192
#define SCAT_CHUNK 4096
#define SCAT_NB 313

__device__ __forceinline__ unsigned short f2bf(float f) {
    unsigned u = __float_as_uint(f);
    unsigned r = u + 0x7fff + ((u >> 16) & 1);   // RNE
    return (unsigned short)(r >> 16);
}
__device__ __forceinline__ float bflo(unsigned a) { return __uint_as_float(a << 16); }
__device__ __forceinline__ float bfhi(unsigned a) { return __uint_as_float(a & 0xffff0000u); }

// ---------------- GEMM: z = h @ W_fc^T  (M=80000, N=64, K=512), bf16 output ----------------
__global__ __launch_bounds__(256) void gemm_z(const float* __restrict__ h,
                                              const float* __restrict__ W,
                                              unsigned short* __restrict__ zb) {
    __shared__ float sh[32][68];
    __shared__ float sw[32][68];
    const int t  = threadIdx.x;
    const int tx = t & 15;
    const int ty = t >> 4;
    const int nbase = blockIdx.x * 64;

    float acc[4][4] = {};

    const int ld_row = t >> 3;
    const int ld_k4  = (t & 7) * 4;

    for (int kc = 0; kc < IN_DIM; kc += 32) {
        #pragma unroll
        for (int rp = 0; rp < 2; ++rp) {
            const int n = ld_row + rp * 32;
            const float4 v = *(const float4*)&h[(size_t)(nbase + n) * IN_DIM + kc + ld_k4];
            sh[ld_k4 + 0][n] = v.x; sh[ld_k4 + 1][n] = v.y;
            sh[ld_k4 + 2][n] = v.z; sh[ld_k4 + 3][n] = v.w;
            const float4 w = *(const float4*)&W[(size_t)n * IN_DIM + kc + ld_k4];
            sw[ld_k4 + 0][n] = w.x; sw[ld_k4 + 1][n] = w.y;
            sw[ld_k4 + 2][n] = w.z; sw[ld_k4 + 3][n] = w.w;
        }
        __syncthreads();
        #pragma unroll
        for (int k = 0; k < 32; ++k) {
            const float4 hv = *(const float4*)&sh[k][ty * 4];
            const float4 wv = *(const float4*)&sw[k][tx * 4];
            const float hr[4] = {hv.x, hv.y, hv.z, hv.w};
            const float wr[4] = {wv.x, wv.y, wv.z, wv.w};
            #pragma unroll
            for (int r = 0; r < 4; ++r)
                #pragma unroll
                for (int c = 0; c < 4; ++c)
                    acc[r][c] += hr[r] * wr[c];
        }
        __syncthreads();
    }
    #pragma unroll
    for (int r = 0; r < 4; ++r) {
        const unsigned lo = (unsigned)f2bf(acc[r][0]) | ((unsigned)f2bf(acc[r][1]) << 16);
        const unsigned hi = (unsigned)f2bf(acc[r][2]) | ((unsigned)f2bf(acc[r][3]) << 16);
        uint2 o = {lo, hi};
        *(uint2*)&zb[((size_t)(nbase + ty * 4 + r) << 6) + (tx << 2)] = o;
    }
}

// ---------------- per-node attention scores (reads bf16 z) ----------------
__global__ __launch_bounds__(256) void attn_scores(const unsigned short* __restrict__ zb,
                                                   const float* __restrict__ pos,
                                                   const float* __restrict__ Wa,
                                                   float* __restrict__ el,
                                                   float* __restrict__ er) {
    const int n = blockIdx.x * 256 + threadIdx.x;
    if (n >= N_NODES) return;
    const unsigned short* zr = &zb[(size_t)n << 6];
    float a = 0.f, b = 0.f;
    #pragma unroll
    for (int j = 0; j < OUT_DIM; j += 8) {
        const uint4 v = *(const uint4*)&zr[j];
        const float z0 = bflo(v.x), z1 = bfhi(v.x), z2 = bflo(v.y), z3 = bfhi(v.y);
        const float z4 = bflo(v.z), z5 = bfhi(v.z), z6 = bflo(v.w), z7 = bfhi(v.w);
        a += z0 * Wa[j] + z1 * Wa[j + 1] + z2 * Wa[j + 2] + z3 * Wa[j + 3]
           + z4 * Wa[j + 4] + z5 * Wa[j + 5] + z6 * Wa[j + 6] + z7 * Wa[j + 7];
        b += z0 * Wa[OUT_DIM + j] + z1 * Wa[OUT_DIM + j + 1] + z2 * Wa[OUT_DIM + j + 2]
           + z3 * Wa[OUT_DIM + j + 3] + z4 * Wa[OUT_DIM + j + 4] + z5 * Wa[OUT_DIM + j + 5]
           + z6 * Wa[OUT_DIM + j + 6] + z7 * Wa[OUT_DIM + j + 7];
    }
    const float* pr = &pos[(size_t)n * POS_DIM];
    #pragma unroll
    for (int p = 0; p < POS_DIM; ++p) {
        a += pr[p] * Wa[2 * OUT_DIM + p];
        b += pr[p] * Wa[2 * OUT_DIM + POS_DIM + p];
    }
    el[n] = a;
    er[n] = b;
}

// ---------------- bucket histogram ----------------
__global__ __launch_bounds__(256) void bucket_hist(const int* __restrict__ dst,
                                                   int* __restrict__ bcnt) {
    __shared__ int hh[NB_BUCKET + 7];
    const int t = threadIdx.x;
    for (int i = t; i < NB_BUCKET; i += 256) hh[i] = 0;
    __syncthreads();
    const int e0 = blockIdx.x * 4096 + t * 4;
    #pragma unroll
    for (int rp = 0; rp < 4; ++rp) {
        const int e = e0 + rp * 1024;
        if (e + 3 < E_EDGES) {
            const int4 d4 = *(const int4*)&dst[e];
            atomicAdd(&hh[d4.x >> 8], 1);
            atomicAdd(&hh[d4.y >> 8], 1);
            atomicAdd(&hh[d4.z >> 8], 1);
            atomicAdd(&hh[d4.w >> 8], 1);
        } else {
            for (int j = 0; j < 4; ++j)
                if (e + j < E_EDGES) atomicAdd(&hh[dst[e + j] >> 8], 1);
        }
    }
    __syncthreads();
    for (int i = t; i < NB_BUCKET; i += 256) {
        const int c = hh[i];
        if (c) atomicAdd(&bcnt[i], c);
    }
}

// ---------------- scan 313 bucket counts ----------------
__global__ __launch_bounds__(64) void bucket_scan(const int* __restrict__ bcnt,
                                                  int* __restrict__ bstart,
                                                  int* __restrict__ bcur) {
    const int t = threadIdx.x;
    int c[5];
    int s = 0;
    #pragma unroll
    for (int j = 0; j < 5; ++j) {
        const int i = t * 5 + j;
        c[j] = (i < NB_BUCKET) ? bcnt[i] : 0;
        s += c[j];
    }
    int ps = s;
    #pragma unroll
    for (int off = 1; off < 64; off <<= 1) {
        const int u = __shfl_up(ps, off);
        if (t >= off) ps += u;
    }
    int run = ps - s;
    #pragma unroll
    for (int j = 0; j < 5; ++j) {
        const int i = t * 5 + j;
        if (i < NB_BUCKET) {
            bstart[i] = run;
            bcur[i]   = run;
            run += c[j];
        }
    }
    if (t == 63) bstart[NB_BUCKET] = E_EDGES;
}

// ---------------- pass 1: block-aggregated scatter ----------------
__global__ __launch_bounds__(256) void bucket_scatter_agg(const int* __restrict__ src,
                                                          const int* __restrict__ dst,
                                                          int* __restrict__ bcur,
                                                          int* __restrict__ ebuf) {
    __shared__ int hh[NB_BUCKET];
    __shared__ int gb[NB_BUCKET];
    const int t = threadIdx.x;
    const int e0 = blockIdx.x * SCAT_CHUNK;

    for (int i = t; i < NB_BUCKET; i += 256) hh[i] = 0;
    __syncthreads();

    int key[16];
    short bk[16];
    short lr[16];
    #pragma unroll
    for (int r = 0; r < 16; ++r) {
        const int e = e0 + r * 256 + t;
        if (e < E_EDGES) {
            const int d = dst[e];
            const int s = src[e];
            bk[r]  = (short)(d >> 8);
            key[r] = (s << 8) | (d & 255);
            lr[r]  = (short)atomicAdd(&hh[d >> 8], 1);
        } else {
            bk[r] = -1;
        }
    }
    __syncthreads();

    for (int i = t; i < NB_BUCKET; i += 256) {
        const int c = hh[i];
        gb[i] = c ? atomicAdd(&bcur[i], c) : 0;
    }
    __syncthreads();

    #pragma unroll
    for (int r = 0; r < 16; ++r) {
        if (bk[r] >= 0) {
            ebuf[gb[bk[r]] + lr[r]] = key[r];
        }
    }
}

// ---------------- pass 2: per-bucket CSR build, in place ----------------
__global__ __launch_bounds__(256) void bucket_csr(int* __restrict__ ebuf,
                                                  const int* __restrict__ bstart,
                                                  int* __restrict__ offs) {
    __shared__ int se[LDS_EDGE_CAP];
    __shared__ int cnt[256];
    __shared__ int cur[256];
    __shared__ int wt[4];
    const int b = blockIdx.x;
    const int t = threadIdx.x;
    const int lane = t & 63;
    const int w = t >> 6;
    const int lo = bstart[b];
    const int ne = bstart[b + 1] - lo;

    cnt[t] = 0;
    __syncthreads();

    int ovf[8];
    int novf = 0;
    for (int i = t; i < ne; i += 256) {
        const int k = ebuf[lo + i];
        atomicAdd(&cnt[k & 255], 1);
        if (i < LDS_EDGE_CAP) se[i] = k;
        else if (novf < 8) ovf[novf++] = k;
    }
    __syncthreads();

    const int v = cnt[t];
    int s = v;
    #pragma unroll
    for (int off = 1; off < 64; off <<= 1) {
        const int u = __shfl_up(s, off);
        if (lane >= off) s += u;
    }
    if (lane == 63) wt[w] = s;
    __syncthreads();
    int base = 0;
    #pragma unroll
    for (int i = 0; i < 4; ++i)
        if (i < w) base += wt[i];
    const int excl = base + s - v;
    cur[t] = excl;
    const int node = b * 256 + t;
    if (node < N_NODES) offs[node] = lo + excl;
    if (b == NB_BUCKET - 1 && t == 0) offs[N_NODES] = E_EDGES;
    __syncthreads();

    const int nst = (ne < LDS_EDGE_CAP) ? ne : LDS_EDGE_CAP;
    for (int i = t; i < nst; i += 256) {
        const int k = se[i];
        const int p = atomicAdd(&cur[k & 255], 1);
        ebuf[lo + p] = k >> 8;
    }
    for (int j = 0; j < novf; ++j) {
        const int k = ovf[j];
        const int p = atomicAdd(&cur[k & 255], 1);
        ebuf[lo + p] = k >> 8;
    }
}

// ---------------- edge softmax + aggregate: one wave per dst node, bf16 z ----------------
// lane = (half, dim-pair): 2 edges per load instruction, 4 edges per inner iter.
__global__ __launch_bounds__(256) void aggregate(const int* __restrict__ offs,
                                                 const int* __restrict__ esrc,
                                                 const float* __restrict__ el,
                                                 const float* __restrict__ er,
                                                 const unsigned short* __restrict__ zb,
                                                 float* __restrict__ out) {
    const int wave = (int)((blockIdx.x * 256 + threadIdx.x) >> 6);
    const int lane = threadIdx.x & 63;
    if (wave >= N_NODES) return;
    const int d = wave;
    const int start = offs[d];
    const int end   = offs[d + 1];
    const int ne    = end - start;
    const float erd = er[d];
    const int dp   = lane & 31;
    const int half = lane >> 5;

    float accx = 0.f, accy = 0.f;
    float dsum = 0.f;

    if (ne <= 64) {
        // fast path: single batch, one el-gather, one exp
        int s_i = 0;
        float eraw = -INFINITY;
        if (lane < ne) {
            s_i = esrc[start + lane];
            float e = el[s_i] + erd;
            eraw = e > 0.f ? e : NEG_SLOPE * e;
        }
        float m = eraw;
        #pragma unroll
        for (int off = 32; off; off >>= 1) m = fmaxf(m, __shfl_xor(m, off));
        float ex_i = (lane < ne) ? __expf(eraw - m) : 0.f;
        dsum = ex_i;
        #pragma unroll
        for (int off = 32; off; off >>= 1) dsum += __shfl_xor(dsum, off);

        const int clr = (ne + 3) & ~3;
        for (int bb = 0; bb < clr; bb += 4) {
            const float wA = __shfl(ex_i, bb + half);
            const int   sA = __shfl(s_i,  bb + half);
            const float wB = __shfl(ex_i, bb + 2 + half);
            const int   sB = __shfl(s_i,  bb + 2 + half);
            const unsigned a = *(const unsigned*)&zb[((size_t)sA << 6) + (dp << 1)];
            const unsigned b = *(const unsigned*)&zb[((size_t)sB << 6) + (dp << 1)];
            accx += wA * bflo(a); accy += wA * bfhi(a);
            accx += wB * bflo(b); accy += wB * bfhi(b);
        }
    } else {
        // generic 2-pass
        float m = -INFINITY;
        for (int i = start + lane; i < end; i += 64) {
            const int s = esrc[i];
            float e = el[s] + erd;
            e = e > 0.f ? e : NEG_SLOPE * e;
            m = fmaxf(m, e);
        }
        #pragma unroll
        for (int off = 32; off; off >>= 1) m = fmaxf(m, __shfl_xor(m, off));

        for (int base = start; base < end; base += 64) {
            const int cl = min(64, end - base);
            int s_i = 0;
            float ex_i = 0.f;
            if (lane < cl) {
                s_i = esrc[base + lane];
                float e = el[s_i] + erd;
                e = e > 0.f ? e : NEG_SLOPE * e;
                ex_i = __expf(e - m);
            }
            dsum += ex_i;
            const int clr = (cl + 3) & ~3;
            for (int bb = 0; bb < clr; bb += 4) {
                const float wA = __shfl(ex_i, bb + half);
                const int   sA = __shfl(s_i,  bb + half);
                const float wB = __shfl(ex_i, bb + 2 + half);
                const int   sB = __shfl(s_i,  bb + 2 + half);
                const unsigned a = *(const unsigned*)&zb[((size_t)sA << 6) + (dp << 1)];
                const unsigned b = *(const unsigned*)&zb[((size_t)sB << 6) + (dp << 1)];
                accx += wA * bflo(a); accy += wA * bfhi(a);
                accx += wB * bflo(b); accy += wB * bfhi(b);
            }
        }
        #pragma unroll
        for (int off = 32; off; off >>= 1) dsum += __shfl_xor(dsum, off);
    }

    // combine the two edge-halves (same dims live in lane and lane^32)
    accx += __shfl_xor(accx, 32);
    accy += __shfl_xor(accy, 32);

    if (half == 0) {
        const float inv = (ne > 0) ? (1.f / dsum) : 0.f;
        float2 o = {accx * inv, accy * inv};
        *(float2*)&out[((size_t)d << 6) + (dp << 1)] = o;
    }
}

// ---------------- launch ----------------
extern "C" void kernel_launch(void* const* d_in, const int* in_sizes, int n_in,
                              void* d_out, int out_size, void* d_ws, size_t ws_size,
                              hipStream_t stream) {
    const float* h   = (const float*)d_in[0];
    const float* pos = (const float*)d_in[1];
    const int* src   = (const int*)d_in[2];
    const int* dst   = (const int*)d_in[3];
    const float* Wfc = (const float*)d_in[4];
    const float* Wa  = (const float*)d_in[5];
    float* out = (float*)d_out;

    char* ws = (char*)d_ws;
    unsigned short* zb = (unsigned short*)(ws);     // 10,240,000 B (N*64 bf16)
    float* el     = (float*)(ws + 10240000);        // 320,000 B
    float* er     = (float*)(ws + 10560000);        // 320,000 B
    int*   offs   = (int*)  (ws + 10880000);        // 320,016 B
    int*   ebuf   = (int*)  (ws + 11200016);        // 5,120,000 B
    int*   bcnt   = (int*)  (ws + 16320016);        // 1,280 B
    int*   bstart = (int*)  (ws + 16321296);        // 1,280 B
    int*   bcur   = (int*)  (ws + 16322576);        // 1,280 B

    gemm_z<<<N_NODES / 64, 256, 0, stream>>>(h, Wfc, zb);
    attn_scores<<<(N_NODES + 255) / 256, 256, 0, stream>>>(zb, pos, Wa, el, er);
    hipMemsetAsync(bcnt, 0, NB_BUCKET * sizeof(int), stream);
    bucket_hist<<<320, 256, 0, stream>>>(dst, bcnt);
    bucket_scan<<<1, 64, 0, stream>>>(bcnt, bstart, bcur);
    bucket_scatter_agg<<<SCAT_NB, 256, 0, stream>>>(src, dst, bcur, ebuf);
    bucket_csr<<<NB_BUCKET, 256, 0, stream>>>(ebuf, bstart, offs);
    aggregate<<<N_NODES / 4, 256, 0, stream>>>(offs, ebuf, el, er, zb, out);
}

// Round 6
// 128.687 us; speedup vs baseline: 5.6048x; 1.3790x over previous
//
#include <hip/hip_runtime.h>
#include <math.h>

#define N_NODES 80000
#define E_EDGES 1280000
#define IN_DIM  512
#define OUT_DIM 64
#define POS_DIM 8
#define NEG_SLOPE 0.01f

#define NB_BUCKET 313          // ceil(80000/256), bucket = dst >> 8
#define LDS_EDGE_CAP 8192
#define SCAT_CHUNK 4096
#define SCAT_NB 313

#define BM 128
#define BK 64
#define LDA 72                 // bf16 elems/row: 144 B, 16B-aligned, even bank-cluster spread
#define LDB 72

typedef __attribute__((ext_vector_type(8))) short short8v;
typedef __attribute__((ext_vector_type(4))) float f32x4;

__device__ __forceinline__ unsigned short f2bf(float f) {
    unsigned u = __float_as_uint(f);
    unsigned r = u + 0x7fff + ((u >> 16) & 1);   // RNE
    return (unsigned short)(r >> 16);
}
__device__ __forceinline__ float bflo(unsigned a) { return __uint_as_float(a << 16); }
__device__ __forceinline__ float bfhi(unsigned a) { return __uint_as_float(a & 0xffff0000u); }

// ---------------- GEMM via MFMA: z = h @ W_fc^T (M=80000,K=512,N=64), bf16 inputs/output ----------------
// 625 blocks x 256 thr (4 waves). Block: 128 rows x 64 cols. Wave: 32x64 = 2x4 tiles of 16x16.
__global__ __launch_bounds__(256) void gemm_z_mfma(const float* __restrict__ h,
                                                   const float* __restrict__ W,
                                                   unsigned short* __restrict__ zb) {
    __shared__ unsigned short sA[BM][LDA];
    __shared__ unsigned short sB[64][LDB];
    const int t    = threadIdx.x;
    const int lane = t & 63;
    const int w    = t >> 6;
    const int row0 = blockIdx.x * BM;
    const int g    = lane >> 4;   // k-group 0..3
    const int rr   = lane & 15;

    f32x4 acc[2][4] = {};

    float4 ra[8];
    float4 rb[4];

    // load chunk 0
    {
        const int k0 = 0;
        #pragma unroll
        for (int i = 0; i < 8; ++i) {
            const int idx = t + i * 256;
            ra[i] = *(const float4*)&h[(size_t)(row0 + (idx >> 4)) * IN_DIM + k0 + ((idx & 15) << 2)];
        }
        #pragma unroll
        for (int i = 0; i < 4; ++i) {
            const int idx = t + i * 256;
            rb[i] = *(const float4*)&W[(size_t)(idx >> 4) * IN_DIM + k0 + ((idx & 15) << 2)];
        }
    }

    for (int c = 0; c < IN_DIM / BK; ++c) {
        __syncthreads();   // previous MFMA reads done before overwrite
        #pragma unroll
        for (int i = 0; i < 8; ++i) {
            const int idx = t + i * 256;
            ushort4 v = {f2bf(ra[i].x), f2bf(ra[i].y), f2bf(ra[i].z), f2bf(ra[i].w)};
            *(ushort4*)&sA[idx >> 4][(idx & 15) << 2] = v;
        }
        #pragma unroll
        for (int i = 0; i < 4; ++i) {
            const int idx = t + i * 256;
            ushort4 v = {f2bf(rb[i].x), f2bf(rb[i].y), f2bf(rb[i].z), f2bf(rb[i].w)};
            *(ushort4*)&sB[idx >> 4][(idx & 15) << 2] = v;
        }
        __syncthreads();

        if (c < IN_DIM / BK - 1) {
            const int k0 = (c + 1) * BK;
            #pragma unroll
            for (int i = 0; i < 8; ++i) {
                const int idx = t + i * 256;
                ra[i] = *(const float4*)&h[(size_t)(row0 + (idx >> 4)) * IN_DIM + k0 + ((idx & 15) << 2)];
            }
            #pragma unroll
            for (int i = 0; i < 4; ++i) {
                const int idx = t + i * 256;
                rb[i] = *(const float4*)&W[(size_t)(idx >> 4) * IN_DIM + k0 + ((idx & 15) << 2)];
            }
        }

        // fragments: A row = w*32 + rt*16 + rr, k = ks*32 + g*8 ; B col = ct*16 + rr
        short8v afr[2][2];
        #pragma unroll
        for (int rt = 0; rt < 2; ++rt)
            #pragma unroll
            for (int ks = 0; ks < 2; ++ks)
                afr[rt][ks] = *(const short8v*)&sA[w * 32 + rt * 16 + rr][ks * 32 + g * 8];
        short8v bfr[4][2];
        #pragma unroll
        for (int ct = 0; ct < 4; ++ct)
            #pragma unroll
            for (int ks = 0; ks < 2; ++ks)
                bfr[ct][ks] = *(const short8v*)&sB[ct * 16 + rr][ks * 32 + g * 8];

        #pragma unroll
        for (int ks = 0; ks < 2; ++ks)
            #pragma unroll
            for (int rt = 0; rt < 2; ++rt)
                #pragma unroll
                for (int ct = 0; ct < 4; ++ct)
                    acc[rt][ct] = __builtin_amdgcn_mfma_f32_16x16x32_bf16(
                        afr[rt][ks], bfr[ct][ks], acc[rt][ct], 0, 0, 0);
    }

    // epilogue: D col = lane&15, row = (lane>>4)*4 + r (m89-verified)
    #pragma unroll
    for (int rt = 0; rt < 2; ++rt)
        #pragma unroll
        for (int ct = 0; ct < 4; ++ct)
            #pragma unroll
            for (int r = 0; r < 4; ++r) {
                const int row = row0 + w * 32 + rt * 16 + g * 4 + r;
                zb[((size_t)row << 6) + ct * 16 + rr] = f2bf(acc[rt][ct][r]);
            }
}

// ---------------- per-node attention scores (reads bf16 z) ----------------
__global__ __launch_bounds__(256) void attn_scores(const unsigned short* __restrict__ zb,
                                                   const float* __restrict__ pos,
                                                   const float* __restrict__ Wa,
                                                   float* __restrict__ el,
                                                   float* __restrict__ er) {
    const int n = blockIdx.x * 256 + threadIdx.x;
    if (n >= N_NODES) return;
    const unsigned short* zr = &zb[(size_t)n << 6];
    float a = 0.f, b = 0.f;
    #pragma unroll
    for (int j = 0; j < OUT_DIM; j += 8) {
        const uint4 v = *(const uint4*)&zr[j];
        const float z0 = bflo(v.x), z1 = bfhi(v.x), z2 = bflo(v.y), z3 = bfhi(v.y);
        const float z4 = bflo(v.z), z5 = bfhi(v.z), z6 = bflo(v.w), z7 = bfhi(v.w);
        a += z0 * Wa[j] + z1 * Wa[j + 1] + z2 * Wa[j + 2] + z3 * Wa[j + 3]
           + z4 * Wa[j + 4] + z5 * Wa[j + 5] + z6 * Wa[j + 6] + z7 * Wa[j + 7];
        b += z0 * Wa[OUT_DIM + j] + z1 * Wa[OUT_DIM + j + 1] + z2 * Wa[OUT_DIM + j + 2]
           + z3 * Wa[OUT_DIM + j + 3] + z4 * Wa[OUT_DIM + j + 4] + z5 * Wa[OUT_DIM + j + 5]
           + z6 * Wa[OUT_DIM + j + 6] + z7 * Wa[OUT_DIM + j + 7];
    }
    const float* pr = &pos[(size_t)n * POS_DIM];
    #pragma unroll
    for (int p = 0; p < POS_DIM; ++p) {
        a += pr[p] * Wa[2 * OUT_DIM + p];
        b += pr[p] * Wa[2 * OUT_DIM + POS_DIM + p];
    }
    el[n] = a;
    er[n] = b;
}

// ---------------- zero bucket counters (avoid fillBuffer dispatch) ----------------
__global__ __launch_bounds__(256) void zero_bcnt(int* __restrict__ bcnt) {
    const int i = blockIdx.x * 256 + threadIdx.x;
    if (i < NB_BUCKET) bcnt[i] = 0;
}

// ---------------- bucket histogram ----------------
__global__ __launch_bounds__(256) void bucket_hist(const int* __restrict__ dst,
                                                   int* __restrict__ bcnt) {
    __shared__ int hh[NB_BUCKET + 7];
    const int t = threadIdx.x;
    for (int i = t; i < NB_BUCKET; i += 256) hh[i] = 0;
    __syncthreads();
    const int e0 = blockIdx.x * 4096 + t * 4;
    #pragma unroll
    for (int rp = 0; rp < 4; ++rp) {
        const int e = e0 + rp * 1024;
        if (e + 3 < E_EDGES) {
            const int4 d4 = *(const int4*)&dst[e];
            atomicAdd(&hh[d4.x >> 8], 1);
            atomicAdd(&hh[d4.y >> 8], 1);
            atomicAdd(&hh[d4.z >> 8], 1);
            atomicAdd(&hh[d4.w >> 8], 1);
        } else {
            for (int j = 0; j < 4; ++j)
                if (e + j < E_EDGES) atomicAdd(&hh[dst[e + j] >> 8], 1);
        }
    }
    __syncthreads();
    for (int i = t; i < NB_BUCKET; i += 256) {
        const int c = hh[i];
        if (c) atomicAdd(&bcnt[i], c);
    }
}

// ---------------- scan 313 bucket counts ----------------
__global__ __launch_bounds__(64) void bucket_scan(const int* __restrict__ bcnt,
                                                  int* __restrict__ bstart,
                                                  int* __restrict__ bcur) {
    const int t = threadIdx.x;
    int c[5];
    int s = 0;
    #pragma unroll
    for (int j = 0; j < 5; ++j) {
        const int i = t * 5 + j;
        c[j] = (i < NB_BUCKET) ? bcnt[i] : 0;
        s += c[j];
    }
    int ps = s;
    #pragma unroll
    for (int off = 1; off < 64; off <<= 1) {
        const int u = __shfl_up(ps, off);
        if (t >= off) ps += u;
    }
    int run = ps - s;
    #pragma unroll
    for (int j = 0; j < 5; ++j) {
        const int i = t * 5 + j;
        if (i < NB_BUCKET) {
            bstart[i] = run;
            bcur[i]   = run;
            run += c[j];
        }
    }
    if (t == 63) bstart[NB_BUCKET] = E_EDGES;
}

// ---------------- pass 1: block-aggregated scatter ----------------
__global__ __launch_bounds__(256) void bucket_scatter_agg(const int* __restrict__ src,
                                                          const int* __restrict__ dst,
                                                          int* __restrict__ bcur,
                                                          int* __restrict__ ebuf) {
    __shared__ int hh[NB_BUCKET];
    __shared__ int gb[NB_BUCKET];
    const int t = threadIdx.x;
    const int e0 = blockIdx.x * SCAT_CHUNK;

    for (int i = t; i < NB_BUCKET; i += 256) hh[i] = 0;
    __syncthreads();

    int key[16];
    short bk[16];
    short lr[16];
    #pragma unroll
    for (int r = 0; r < 16; ++r) {
        const int e = e0 + r * 256 + t;
        if (e < E_EDGES) {
            const int d = dst[e];
            const int s = src[e];
            bk[r]  = (short)(d >> 8);
            key[r] = (s << 8) | (d & 255);
            lr[r]  = (short)atomicAdd(&hh[d >> 8], 1);
        } else {
            bk[r] = -1;
        }
    }
    __syncthreads();

    for (int i = t; i < NB_BUCKET; i += 256) {
        const int c = hh[i];
        gb[i] = c ? atomicAdd(&bcur[i], c) : 0;
    }
    __syncthreads();

    #pragma unroll
    for (int r = 0; r < 16; ++r) {
        if (bk[r] >= 0) {
            ebuf[gb[bk[r]] + lr[r]] = key[r];
        }
    }
}

// ---------------- pass 2: per-bucket CSR build, in place ----------------
__global__ __launch_bounds__(256) void bucket_csr(int* __restrict__ ebuf,
                                                  const int* __restrict__ bstart,
                                                  int* __restrict__ offs) {
    __shared__ int se[LDS_EDGE_CAP];
    __shared__ int cnt[256];
    __shared__ int cur[256];
    __shared__ int wt[4];
    const int b = blockIdx.x;
    const int t = threadIdx.x;
    const int lane = t & 63;
    const int w = t >> 6;
    const int lo = bstart[b];
    const int ne = bstart[b + 1] - lo;

    cnt[t] = 0;
    __syncthreads();

    int ovf[8];
    int novf = 0;
    for (int i = t; i < ne; i += 256) {
        const int k = ebuf[lo + i];
        atomicAdd(&cnt[k & 255], 1);
        if (i < LDS_EDGE_CAP) se[i] = k;
        else if (novf < 8) ovf[novf++] = k;
    }
    __syncthreads();

    const int v = cnt[t];
    int s = v;
    #pragma unroll
    for (int off = 1; off < 64; off <<= 1) {
        const int u = __shfl_up(s, off);
        if (lane >= off) s += u;
    }
    if (lane == 63) wt[w] = s;
    __syncthreads();
    int base = 0;
    #pragma unroll
    for (int i = 0; i < 4; ++i)
        if (i < w) base += wt[i];
    const int excl = base + s - v;
    cur[t] = excl;
    const int node = b * 256 + t;
    if (node < N_NODES) offs[node] = lo + excl;
    if (b == NB_BUCKET - 1 && t == 0) offs[N_NODES] = E_EDGES;
    __syncthreads();

    const int nst = (ne < LDS_EDGE_CAP) ? ne : LDS_EDGE_CAP;
    for (int i = t; i < nst; i += 256) {
        const int k = se[i];
        const int p = atomicAdd(&cur[k & 255], 1);
        ebuf[lo + p] = k >> 8;
    }
    for (int j = 0; j < novf; ++j) {
        const int k = ovf[j];
        const int p = atomicAdd(&cur[k & 255], 1);
        ebuf[lo + p] = k >> 8;
    }
}

// ---------------- edge softmax + aggregate: one wave per dst node, bf16 z ----------------
__global__ __launch_bounds__(256) void aggregate(const int* __restrict__ offs,
                                                 const int* __restrict__ esrc,
                                                 const float* __restrict__ el,
                                                 const float* __restrict__ er,
                                                 const unsigned short* __restrict__ zb,
                                                 float* __restrict__ out) {
    const int wave = (int)((blockIdx.x * 256 + threadIdx.x) >> 6);
    const int lane = threadIdx.x & 63;
    if (wave >= N_NODES) return;
    const int d = wave;
    const int start = offs[d];
    const int end   = offs[d + 1];
    const int ne    = end - start;
    const float erd = er[d];
    const int dp   = lane & 31;
    const int half = lane >> 5;

    float accx = 0.f, accy = 0.f;
    float dsum = 0.f;

    if (ne <= 64) {
        int s_i = 0;
        float eraw = -INFINITY;
        if (lane < ne) {
            s_i = esrc[start + lane];
            float e = el[s_i] + erd;
            eraw = e > 0.f ? e : NEG_SLOPE * e;
        }
        float m = eraw;
        #pragma unroll
        for (int off = 32; off; off >>= 1) m = fmaxf(m, __shfl_xor(m, off));
        float ex_i = (lane < ne) ? __expf(eraw - m) : 0.f;
        dsum = ex_i;
        #pragma unroll
        for (int off = 32; off; off >>= 1) dsum += __shfl_xor(dsum, off);

        const int clr = (ne + 3) & ~3;
        for (int bb = 0; bb < clr; bb += 4) {
            const float wA = __shfl(ex_i, bb + half);
            const int   sA = __shfl(s_i,  bb + half);
            const float wB = __shfl(ex_i, bb + 2 + half);
            const int   sB = __shfl(s_i,  bb + 2 + half);
            const unsigned a = *(const unsigned*)&zb[((size_t)sA << 6) + (dp << 1)];
            const unsigned b = *(const unsigned*)&zb[((size_t)sB << 6) + (dp << 1)];
            accx += wA * bflo(a); accy += wA * bfhi(a);
            accx += wB * bflo(b); accy += wB * bfhi(b);
        }
    } else {
        float m = -INFINITY;
        for (int i = start + lane; i < end; i += 64) {
            const int s = esrc[i];
            float e = el[s] + erd;
            e = e > 0.f ? e : NEG_SLOPE * e;
            m = fmaxf(m, e);
        }
        #pragma unroll
        for (int off = 32; off; off >>= 1) m = fmaxf(m, __shfl_xor(m, off));

        for (int base = start; base < end; base += 64) {
            const int cl = min(64, end - base);
            int s_i = 0;
            float ex_i = 0.f;
            if (lane < cl) {
                s_i = esrc[base + lane];
                float e = el[s_i] + erd;
                e = e > 0.f ? e : NEG_SLOPE * e;
                ex_i = __expf(e - m);
            }
            dsum += ex_i;
            const int clr = (cl + 3) & ~3;
            for (int bb = 0; bb < clr; bb += 4) {
                const float wA = __shfl(ex_i, bb + half);
                const int   sA = __shfl(s_i,  bb + half);
                const float wB = __shfl(ex_i, bb + 2 + half);
                const int   sB = __shfl(s_i,  bb + 2 + half);
                const unsigned a = *(const unsigned*)&zb[((size_t)sA << 6) + (dp << 1)];
                const unsigned b = *(const unsigned*)&zb[((size_t)sB << 6) + (dp << 1)];
                accx += wA * bflo(a); accy += wA * bfhi(a);
                accx += wB * bflo(b); accy += wB * bfhi(b);
            }
        }
        #pragma unroll
        for (int off = 32; off; off >>= 1) dsum += __shfl_xor(dsum, off);
    }

    accx += __shfl_xor(accx, 32);
    accy += __shfl_xor(accy, 32);

    if (half == 0) {
        const float inv = (ne > 0) ? (1.f / dsum) : 0.f;
        float2 o = {accx * inv, accy * inv};
        *(float2*)&out[((size_t)d << 6) + (dp << 1)] = o;
    }
}

// ---------------- launch ----------------
extern "C" void kernel_launch(void* const* d_in, const int* in_sizes, int n_in,
                              void* d_out, int out_size, void* d_ws, size_t ws_size,
                              hipStream_t stream) {
    const float* h   = (const float*)d_in[0];
    const float* pos = (const float*)d_in[1];
    const int* src   = (const int*)d_in[2];
    const int* dst   = (const int*)d_in[3];
    const float* Wfc = (const float*)d_in[4];
    const float* Wa  = (const float*)d_in[5];
    float* out = (float*)d_out;

    char* ws = (char*)d_ws;
    unsigned short* zb = (unsigned short*)(ws);     // 10,240,000 B (N*64 bf16)
    float* el     = (float*)(ws + 10240000);        // 320,000 B
    float* er     = (float*)(ws + 10560000);        // 320,000 B
    int*   offs   = (int*)  (ws + 10880000);        // 320,016 B
    int*   ebuf   = (int*)  (ws + 11200016);        // 5,120,000 B
    int*   bcnt   = (int*)  (ws + 16320016);        // 1,280 B
    int*   bstart = (int*)  (ws + 16321296);        // 1,280 B
    int*   bcur   = (int*)  (ws + 16322576);        // 1,280 B

    gemm_z_mfma<<<N_NODES / BM, 256, 0, stream>>>(h, Wfc, zb);
    attn_scores<<<(N_NODES + 255) / 256, 256, 0, stream>>>(zb, pos, Wa, el, er);
    zero_bcnt<<<2, 256, 0, stream>>>(bcnt);
    bucket_hist<<<320, 256, 0, stream>>>(dst, bcnt);
    bucket_scan<<<1, 64, 0, stream>>>(bcnt, bstart, bcur);
    bucket_scatter_agg<<<SCAT_NB, 256, 0, stream>>>(src, dst, bcur, ebuf);
    bucket_csr<<<NB_BUCKET, 256, 0, stream>>>(ebuf, bstart, offs);
    aggregate<<<N_NODES / 4, 256, 0, stream>>>(offs, ebuf, el, er, zb, out);
}

// Round 7
// 110.203 us; speedup vs baseline: 6.5449x; 1.1677x over previous
//
#include <hip/hip_runtime.h>
#include <math.h>

#define N_NODES 80000
#define E_EDGES 1280000
#define IN_DIM  512
#define OUT_DIM 64
#define POS_DIM 8
#define NEG_SLOPE 0.01f

#define NB_BUCKET 313          // ceil(80000/256), bucket = dst >> 8
#define BCAP 8192              // fixed region per bucket (mean 4096, sigma 64)
#define SCAT_CHUNK 4096
#define SCAT_NB 313

#define BM 128
#define BK 64
#define LDA 72
#define LDB 72

typedef __attribute__((ext_vector_type(8))) short short8v;
typedef __attribute__((ext_vector_type(4))) float f32x4;

__device__ __forceinline__ unsigned short f2bf(float f) {
    unsigned u = __float_as_uint(f);
    unsigned r = u + 0x7fff + ((u >> 16) & 1);   // RNE
    return (unsigned short)(r >> 16);
}
__device__ __forceinline__ float bflo(unsigned a) { return __uint_as_float(a << 16); }
__device__ __forceinline__ float bfhi(unsigned a) { return __uint_as_float(a & 0xffff0000u); }

// ---- GEMM via MFMA + fused attn scores: z=h@W^T, el=z@wzs+pos@wps, er=z@wzd+pos@wpd ----
// 625 blocks x 256 thr (4 waves). Block: 128 rows x 64 cols. Wave: 32x64 = 2x4 16x16 tiles.
// Block 0 also seeds bcur[i] = i*BCAP for the scatter pass (stream-ordered visibility).
__global__ __launch_bounds__(256) void gemm_fused(const float* __restrict__ h,
                                                  const float* __restrict__ W,
                                                  const float* __restrict__ pos,
                                                  const float* __restrict__ Wa,
                                                  unsigned short* __restrict__ zb,
                                                  float* __restrict__ el,
                                                  float* __restrict__ er,
                                                  int* __restrict__ bcur) {
    __shared__ unsigned short sA[BM][LDA];
    __shared__ unsigned short sB[64][LDB];
    const int t    = threadIdx.x;
    const int lane = t & 63;
    const int w    = t >> 6;
    const int row0 = blockIdx.x * BM;
    const int g    = lane >> 4;   // k-group 0..3
    const int rr   = lane & 15;

    if (blockIdx.x == 0) {
        for (int i = t; i < NB_BUCKET; i += 256) bcur[i] = i * BCAP;
    }

    f32x4 acc[2][4] = {};
    float4 ra[8];
    float4 rb[4];

    {
        #pragma unroll
        for (int i = 0; i < 8; ++i) {
            const int idx = t + i * 256;
            ra[i] = *(const float4*)&h[(size_t)(row0 + (idx >> 4)) * IN_DIM + ((idx & 15) << 2)];
        }
        #pragma unroll
        for (int i = 0; i < 4; ++i) {
            const int idx = t + i * 256;
            rb[i] = *(const float4*)&W[(size_t)(idx >> 4) * IN_DIM + ((idx & 15) << 2)];
        }
    }

    for (int c = 0; c < IN_DIM / BK; ++c) {
        __syncthreads();
        #pragma unroll
        for (int i = 0; i < 8; ++i) {
            const int idx = t + i * 256;
            ushort4 v = {f2bf(ra[i].x), f2bf(ra[i].y), f2bf(ra[i].z), f2bf(ra[i].w)};
            *(ushort4*)&sA[idx >> 4][(idx & 15) << 2] = v;
        }
        #pragma unroll
        for (int i = 0; i < 4; ++i) {
            const int idx = t + i * 256;
            ushort4 v = {f2bf(rb[i].x), f2bf(rb[i].y), f2bf(rb[i].z), f2bf(rb[i].w)};
            *(ushort4*)&sB[idx >> 4][(idx & 15) << 2] = v;
        }
        __syncthreads();

        if (c < IN_DIM / BK - 1) {
            const int k0 = (c + 1) * BK;
            #pragma unroll
            for (int i = 0; i < 8; ++i) {
                const int idx = t + i * 256;
                ra[i] = *(const float4*)&h[(size_t)(row0 + (idx >> 4)) * IN_DIM + k0 + ((idx & 15) << 2)];
            }
            #pragma unroll
            for (int i = 0; i < 4; ++i) {
                const int idx = t + i * 256;
                rb[i] = *(const float4*)&W[(size_t)(idx >> 4) * IN_DIM + k0 + ((idx & 15) << 2)];
            }
        }

        short8v afr[2][2];
        #pragma unroll
        for (int rt = 0; rt < 2; ++rt)
            #pragma unroll
            for (int ks = 0; ks < 2; ++ks)
                afr[rt][ks] = *(const short8v*)&sA[w * 32 + rt * 16 + rr][ks * 32 + g * 8];
        short8v bfr[4][2];
        #pragma unroll
        for (int ct = 0; ct < 4; ++ct)
            #pragma unroll
            for (int ks = 0; ks < 2; ++ks)
                bfr[ct][ks] = *(const short8v*)&sB[ct * 16 + rr][ks * 32 + g * 8];

        #pragma unroll
        for (int ks = 0; ks < 2; ++ks)
            #pragma unroll
            for (int rt = 0; rt < 2; ++rt)
                #pragma unroll
                for (int ct = 0; ct < 4; ++ct)
                    acc[rt][ct] = __builtin_amdgcn_mfma_f32_16x16x32_bf16(
                        afr[rt][ks], bfr[ct][ks], acc[rt][ct], 0, 0, 0);
    }

    // z store: D col = lane&15, row = (lane>>4)*4 + r
    #pragma unroll
    for (int rt = 0; rt < 2; ++rt)
        #pragma unroll
        for (int ct = 0; ct < 4; ++ct)
            #pragma unroll
            for (int r = 0; r < 4; ++r) {
                const int row = row0 + w * 32 + rt * 16 + g * 4 + r;
                zb[((size_t)row << 6) + ct * 16 + rr] = f2bf(acc[rt][ct][r]);
            }

    // fused attn scores from fp32 acc
    float wzs_c[4], wzd_c[4];
    #pragma unroll
    for (int ct = 0; ct < 4; ++ct) {
        wzs_c[ct] = Wa[ct * 16 + rr];
        wzd_c[ct] = Wa[OUT_DIM + ct * 16 + rr];
    }
    #pragma unroll
    for (int rt = 0; rt < 2; ++rt)
        #pragma unroll
        for (int r = 0; r < 4; ++r) {
            float pe = 0.f, pd = 0.f;
            #pragma unroll
            for (int ct = 0; ct < 4; ++ct) {
                pe += acc[rt][ct][r] * wzs_c[ct];
                pd += acc[rt][ct][r] * wzd_c[ct];
            }
            #pragma unroll
            for (int off = 8; off; off >>= 1) {
                pe += __shfl_xor(pe, off);
                pd += __shfl_xor(pd, off);
            }
            if (rr == 0) {
                const int row = row0 + w * 32 + rt * 16 + g * 4 + r;
                const float4 p0 = *(const float4*)&pos[(size_t)row * POS_DIM];
                const float4 p1 = *(const float4*)&pos[(size_t)row * POS_DIM + 4];
                const float4 s0 = *(const float4*)&Wa[2 * OUT_DIM];
                const float4 s1 = *(const float4*)&Wa[2 * OUT_DIM + 4];
                const float4 d0 = *(const float4*)&Wa[2 * OUT_DIM + POS_DIM];
                const float4 d1 = *(const float4*)&Wa[2 * OUT_DIM + POS_DIM + 4];
                el[row] = pe + p0.x * s0.x + p0.y * s0.y + p0.z * s0.z + p0.w * s0.w
                              + p1.x * s1.x + p1.y * s1.y + p1.z * s1.z + p1.w * s1.w;
                er[row] = pd + p0.x * d0.x + p0.y * d0.y + p0.z * d0.z + p0.w * d0.w
                              + p1.x * d1.x + p1.y * d1.y + p1.z * d1.z + p1.w * d1.w;
            }
        }
}

// ---------------- pass 1: block-aggregated scatter into fixed bucket regions ----------------
__global__ __launch_bounds__(256) void bucket_scatter_agg(const int* __restrict__ src,
                                                          const int* __restrict__ dst,
                                                          int* __restrict__ bcur,
                                                          int* __restrict__ ebuf) {
    __shared__ int hh[NB_BUCKET];
    __shared__ int gb[NB_BUCKET];
    const int t = threadIdx.x;
    const int e0 = blockIdx.x * SCAT_CHUNK;

    for (int i = t; i < NB_BUCKET; i += 256) hh[i] = 0;
    __syncthreads();

    int key[16];
    short bk[16];
    short lr[16];
    #pragma unroll
    for (int r = 0; r < 16; ++r) {
        const int e = e0 + r * 256 + t;
        if (e < E_EDGES) {
            const int d = dst[e];
            const int s = src[e];
            bk[r]  = (short)(d >> 8);
            key[r] = (s << 8) | (d & 255);
            lr[r]  = (short)atomicAdd(&hh[d >> 8], 1);
        } else {
            bk[r] = -1;
        }
    }
    __syncthreads();

    for (int i = t; i < NB_BUCKET; i += 256) {
        const int c = hh[i];
        gb[i] = c ? atomicAdd(&bcur[i], c) : 0;
    }
    __syncthreads();

    #pragma unroll
    for (int r = 0; r < 16; ++r) {
        if (bk[r] >= 0) {
            ebuf[gb[bk[r]] + lr[r]] = key[r];
        }
    }
}

// ---------------- pass 2: per-bucket CSR build, in place ----------------
__global__ __launch_bounds__(256) void bucket_csr(int* __restrict__ ebuf,
                                                  const int* __restrict__ bcur,
                                                  int* __restrict__ offs,
                                                  int* __restrict__ oend) {
    __shared__ int se[BCAP];
    __shared__ int cnt[256];
    __shared__ int cur[256];
    __shared__ int wt[4];
    const int b = blockIdx.x;
    const int t = threadIdx.x;
    const int lane = t & 63;
    const int w = t >> 6;
    const int lo = b * BCAP;
    const int ne = bcur[b] - lo;

    cnt[t] = 0;
    __syncthreads();

    for (int i = t; i < ne; i += 256) {
        const int k = ebuf[lo + i];
        atomicAdd(&cnt[k & 255], 1);
        se[i] = k;
    }
    __syncthreads();

    const int v = cnt[t];
    int s = v;
    #pragma unroll
    for (int off = 1; off < 64; off <<= 1) {
        const int u = __shfl_up(s, off);
        if (lane >= off) s += u;
    }
    if (lane == 63) wt[w] = s;
    __syncthreads();
    int base = 0;
    #pragma unroll
    for (int i = 0; i < 4; ++i)
        if (i < w) base += wt[i];
    const int excl = base + s - v;
    cur[t] = excl;
    const int node = b * 256 + t;
    if (node < N_NODES) {
        offs[node] = lo + excl;
        oend[node] = lo + excl + v;
    }
    __syncthreads();

    for (int i = t; i < ne; i += 256) {
        const int k = se[i];
        const int p = atomicAdd(&cur[k & 255], 1);
        ebuf[lo + p] = k >> 8;
    }
}

// ---------------- edge softmax + aggregate: one wave per dst node, bf16 z ----------------
__global__ __launch_bounds__(256) void aggregate(const int* __restrict__ offs,
                                                 const int* __restrict__ oend,
                                                 const int* __restrict__ esrc,
                                                 const float* __restrict__ el,
                                                 const float* __restrict__ er,
                                                 const unsigned short* __restrict__ zb,
                                                 float* __restrict__ out) {
    const int wave = (int)((blockIdx.x * 256 + threadIdx.x) >> 6);
    const int lane = threadIdx.x & 63;
    if (wave >= N_NODES) return;
    const int d = wave;
    const int start = offs[d];
    const int end   = oend[d];
    const int ne    = end - start;
    const float erd = er[d];
    const int dp   = lane & 31;
    const int half = lane >> 5;

    float accx = 0.f, accy = 0.f;
    float dsum = 0.f;

    if (ne <= 64) {
        int s_i = 0;
        float eraw = -INFINITY;
        if (lane < ne) {
            s_i = esrc[start + lane];
            float e = el[s_i] + erd;
            eraw = e > 0.f ? e : NEG_SLOPE * e;
        }
        float m = eraw;
        #pragma unroll
        for (int off = 32; off; off >>= 1) m = fmaxf(m, __shfl_xor(m, off));
        float ex_i = (lane < ne) ? __expf(eraw - m) : 0.f;
        dsum = ex_i;
        #pragma unroll
        for (int off = 32; off; off >>= 1) dsum += __shfl_xor(dsum, off);

        const int clr = (ne + 3) & ~3;
        for (int bb = 0; bb < clr; bb += 4) {
            const float wA = __shfl(ex_i, bb + half);
            const int   sA = __shfl(s_i,  bb + half);
            const float wB = __shfl(ex_i, bb + 2 + half);
            const int   sB = __shfl(s_i,  bb + 2 + half);
            const unsigned a = *(const unsigned*)&zb[((size_t)sA << 6) + (dp << 1)];
            const unsigned b = *(const unsigned*)&zb[((size_t)sB << 6) + (dp << 1)];
            accx += wA * bflo(a); accy += wA * bfhi(a);
            accx += wB * bflo(b); accy += wB * bfhi(b);
        }
    } else {
        float m = -INFINITY;
        for (int i = start + lane; i < end; i += 64) {
            const int s = esrc[i];
            float e = el[s] + erd;
            e = e > 0.f ? e : NEG_SLOPE * e;
            m = fmaxf(m, e);
        }
        #pragma unroll
        for (int off = 32; off; off >>= 1) m = fmaxf(m, __shfl_xor(m, off));

        for (int base = start; base < end; base += 64) {
            const int cl = min(64, end - base);
            int s_i = 0;
            float ex_i = 0.f;
            if (lane < cl) {
                s_i = esrc[base + lane];
                float e = el[s_i] + erd;
                e = e > 0.f ? e : NEG_SLOPE * e;
                ex_i = __expf(e - m);
            }
            dsum += ex_i;
            const int clr = (cl + 3) & ~3;
            for (int bb = 0; bb < clr; bb += 4) {
                const float wA = __shfl(ex_i, bb + half);
                const int   sA = __shfl(s_i,  bb + half);
                const float wB = __shfl(ex_i, bb + 2 + half);
                const int   sB = __shfl(s_i,  bb + 2 + half);
                const unsigned a = *(const unsigned*)&zb[((size_t)sA << 6) + (dp << 1)];
                const unsigned b = *(const unsigned*)&zb[((size_t)sB << 6) + (dp << 1)];
                accx += wA * bflo(a); accy += wA * bfhi(a);
                accx += wB * bflo(b); accy += wB * bfhi(b);
            }
        }
        #pragma unroll
        for (int off = 32; off; off >>= 1) dsum += __shfl_xor(dsum, off);
    }

    accx += __shfl_xor(accx, 32);
    accy += __shfl_xor(accy, 32);

    if (half == 0) {
        const float inv = (ne > 0) ? (1.f / dsum) : 0.f;
        float2 o = {accx * inv, accy * inv};
        *(float2*)&out[((size_t)d << 6) + (dp << 1)] = o;
    }
}

// ---------------- launch ----------------
extern "C" void kernel_launch(void* const* d_in, const int* in_sizes, int n_in,
                              void* d_out, int out_size, void* d_ws, size_t ws_size,
                              hipStream_t stream) {
    const float* h   = (const float*)d_in[0];
    const float* pos = (const float*)d_in[1];
    const int* src   = (const int*)d_in[2];
    const int* dst   = (const int*)d_in[3];
    const float* Wfc = (const float*)d_in[4];
    const float* Wa  = (const float*)d_in[5];
    float* out = (float*)d_out;

    char* ws = (char*)d_ws;
    unsigned short* zb = (unsigned short*)(ws);     // 10,240,000 B (N*64 bf16)
    float* el     = (float*)(ws + 10240000);        // 320,000 B
    float* er     = (float*)(ws + 10560000);        // 320,000 B
    int*   offs   = (int*)  (ws + 10880000);        // 320,000 B
    int*   oend   = (int*)  (ws + 11200000);        // 320,000 B
    int*   ebuf   = (int*)  (ws + 11520000);        // 313*8192*4 = 10,256,384 B
    int*   bcur   = (int*)  (ws + 21776384);        // 1,252 B

    gemm_fused<<<N_NODES / BM, 256, 0, stream>>>(h, Wfc, pos, Wa, zb, el, er, bcur);
    bucket_scatter_agg<<<SCAT_NB, 256, 0, stream>>>(src, dst, bcur, ebuf);
    bucket_csr<<<NB_BUCKET, 256, 0, stream>>>(ebuf, bcur, offs, oend);
    aggregate<<<N_NODES / 4, 256, 0, stream>>>(offs, oend, ebuf, el, er, zb, out);
}

// Round 8
// 106.954 us; speedup vs baseline: 6.7437x; 1.0304x over previous
//
#include <hip/hip_runtime.h>
#include <math.h>

#define N_NODES 80000
#define E_EDGES 1280000
#define IN_DIM  512
#define OUT_DIM 64
#define POS_DIM 8
#define NEG_SLOPE 0.01f

#define NB_BUCKET 313          // bucket = dst >> 8
#define BCAP 8192              // fixed region per bucket (mean 4090, sigma ~64)
#define SCAT_CHUNK 4096
#define SCAT_NB 313
#define GEMM_NB 625            // 80000 / 128

#define BM 128
#define BK 64
#define LDA 72
#define LDB 72

typedef __attribute__((ext_vector_type(8))) short short8v;
typedef __attribute__((ext_vector_type(4))) float f32x4;

__device__ __forceinline__ unsigned short f2bf(float f) {
    unsigned u = __float_as_uint(f);
    unsigned r = u + 0x7fff + ((u >> 16) & 1);   // RNE
    return (unsigned short)(r >> 16);
}
__device__ __forceinline__ float bflo(unsigned a) { return __uint_as_float(a << 16); }
__device__ __forceinline__ float bfhi(unsigned a) { return __uint_as_float(a & 0xffff0000u); }

// ---- Kernel A: blocks [0,625) GEMM+attn-scores fused; blocks [625,938) edge scatter ----
__global__ __launch_bounds__(256) void gemm_scatter(const float* __restrict__ h,
                                                    const float* __restrict__ W,
                                                    const float* __restrict__ pos,
                                                    const float* __restrict__ Wa,
                                                    const int* __restrict__ src,
                                                    const int* __restrict__ dst,
                                                    unsigned short* __restrict__ zb,
                                                    float* __restrict__ el,
                                                    float* __restrict__ er,
                                                    int* __restrict__ bcnt,
                                                    int* __restrict__ ebuf) {
    __shared__ unsigned short sA[BM][LDA];
    __shared__ unsigned short sB[64][LDB];
    __shared__ int hh[NB_BUCKET];
    __shared__ int gb[NB_BUCKET];
    const int t = threadIdx.x;

    if (blockIdx.x >= GEMM_NB) {
        // ---------- scatter path ----------
        const int e0 = (blockIdx.x - GEMM_NB) * SCAT_CHUNK;
        for (int i = t; i < NB_BUCKET; i += 256) hh[i] = 0;
        __syncthreads();

        int key[16];
        short bk[16];
        short lr[16];
        #pragma unroll
        for (int r = 0; r < 16; ++r) {
            const int e = e0 + r * 256 + t;
            if (e < E_EDGES) {
                const int d = dst[e];
                const int s = src[e];
                bk[r]  = (short)(d >> 8);
                key[r] = (s << 8) | (d & 255);
                lr[r]  = (short)atomicAdd(&hh[d >> 8], 1);
            } else {
                bk[r] = -1;
            }
        }
        __syncthreads();

        for (int i = t; i < NB_BUCKET; i += 256) {
            const int c = hh[i];
            gb[i] = c ? (i * BCAP + atomicAdd(&bcnt[i], c)) : 0;
        }
        __syncthreads();

        #pragma unroll
        for (int r = 0; r < 16; ++r) {
            if (bk[r] >= 0) {
                ebuf[gb[bk[r]] + lr[r]] = key[r];
            }
        }
        return;
    }

    // ---------- GEMM path ----------
    const int lane = t & 63;
    const int w    = t >> 6;
    const int row0 = blockIdx.x * BM;
    const int g    = lane >> 4;
    const int rr   = lane & 15;

    f32x4 acc[2][4] = {};
    float4 ra[8];
    float4 rb[4];

    {
        #pragma unroll
        for (int i = 0; i < 8; ++i) {
            const int idx = t + i * 256;
            ra[i] = *(const float4*)&h[(size_t)(row0 + (idx >> 4)) * IN_DIM + ((idx & 15) << 2)];
        }
        #pragma unroll
        for (int i = 0; i < 4; ++i) {
            const int idx = t + i * 256;
            rb[i] = *(const float4*)&W[(size_t)(idx >> 4) * IN_DIM + ((idx & 15) << 2)];
        }
    }

    for (int c = 0; c < IN_DIM / BK; ++c) {
        __syncthreads();
        #pragma unroll
        for (int i = 0; i < 8; ++i) {
            const int idx = t + i * 256;
            ushort4 v = {f2bf(ra[i].x), f2bf(ra[i].y), f2bf(ra[i].z), f2bf(ra[i].w)};
            *(ushort4*)&sA[idx >> 4][(idx & 15) << 2] = v;
        }
        #pragma unroll
        for (int i = 0; i < 4; ++i) {
            const int idx = t + i * 256;
            ushort4 v = {f2bf(rb[i].x), f2bf(rb[i].y), f2bf(rb[i].z), f2bf(rb[i].w)};
            *(ushort4*)&sB[idx >> 4][(idx & 15) << 2] = v;
        }
        __syncthreads();

        if (c < IN_DIM / BK - 1) {
            const int k0 = (c + 1) * BK;
            #pragma unroll
            for (int i = 0; i < 8; ++i) {
                const int idx = t + i * 256;
                ra[i] = *(const float4*)&h[(size_t)(row0 + (idx >> 4)) * IN_DIM + k0 + ((idx & 15) << 2)];
            }
            #pragma unroll
            for (int i = 0; i < 4; ++i) {
                const int idx = t + i * 256;
                rb[i] = *(const float4*)&W[(size_t)(idx >> 4) * IN_DIM + k0 + ((idx & 15) << 2)];
            }
        }

        short8v afr[2][2];
        #pragma unroll
        for (int rt = 0; rt < 2; ++rt)
            #pragma unroll
            for (int ks = 0; ks < 2; ++ks)
                afr[rt][ks] = *(const short8v*)&sA[w * 32 + rt * 16 + rr][ks * 32 + g * 8];
        short8v bfr[4][2];
        #pragma unroll
        for (int ct = 0; ct < 4; ++ct)
            #pragma unroll
            for (int ks = 0; ks < 2; ++ks)
                bfr[ct][ks] = *(const short8v*)&sB[ct * 16 + rr][ks * 32 + g * 8];

        #pragma unroll
        for (int ks = 0; ks < 2; ++ks)
            #pragma unroll
            for (int rt = 0; rt < 2; ++rt)
                #pragma unroll
                for (int ct = 0; ct < 4; ++ct)
                    acc[rt][ct] = __builtin_amdgcn_mfma_f32_16x16x32_bf16(
                        afr[rt][ks], bfr[ct][ks], acc[rt][ct], 0, 0, 0);
    }

    #pragma unroll
    for (int rt = 0; rt < 2; ++rt)
        #pragma unroll
        for (int ct = 0; ct < 4; ++ct)
            #pragma unroll
            for (int r = 0; r < 4; ++r) {
                const int row = row0 + w * 32 + rt * 16 + g * 4 + r;
                zb[((size_t)row << 6) + ct * 16 + rr] = f2bf(acc[rt][ct][r]);
            }

    float wzs_c[4], wzd_c[4];
    #pragma unroll
    for (int ct = 0; ct < 4; ++ct) {
        wzs_c[ct] = Wa[ct * 16 + rr];
        wzd_c[ct] = Wa[OUT_DIM + ct * 16 + rr];
    }
    #pragma unroll
    for (int rt = 0; rt < 2; ++rt)
        #pragma unroll
        for (int r = 0; r < 4; ++r) {
            float pe = 0.f, pd = 0.f;
            #pragma unroll
            for (int ct = 0; ct < 4; ++ct) {
                pe += acc[rt][ct][r] * wzs_c[ct];
                pd += acc[rt][ct][r] * wzd_c[ct];
            }
            #pragma unroll
            for (int off = 8; off; off >>= 1) {
                pe += __shfl_xor(pe, off);
                pd += __shfl_xor(pd, off);
            }
            if (rr == 0) {
                const int row = row0 + w * 32 + rt * 16 + g * 4 + r;
                const float4 p0 = *(const float4*)&pos[(size_t)row * POS_DIM];
                const float4 p1 = *(const float4*)&pos[(size_t)row * POS_DIM + 4];
                const float4 s0 = *(const float4*)&Wa[2 * OUT_DIM];
                const float4 s1 = *(const float4*)&Wa[2 * OUT_DIM + 4];
                const float4 d0 = *(const float4*)&Wa[2 * OUT_DIM + POS_DIM];
                const float4 d1 = *(const float4*)&Wa[2 * OUT_DIM + POS_DIM + 4];
                el[row] = pe + p0.x * s0.x + p0.y * s0.y + p0.z * s0.z + p0.w * s0.w
                              + p1.x * s1.x + p1.y * s1.y + p1.z * s1.z + p1.w * s1.w;
                er[row] = pd + p0.x * d0.x + p0.y * d0.y + p0.z * d0.z + p0.w * d0.w
                              + p1.x * d1.x + p1.y * d1.y + p1.z * d1.z + p1.w * d1.w;
            }
        }
}

// ---------------- per-bucket CSR build, in place ----------------
__global__ __launch_bounds__(256) void bucket_csr(int* __restrict__ ebuf,
                                                  const int* __restrict__ bcnt,
                                                  int* __restrict__ offs,
                                                  int* __restrict__ oend) {
    __shared__ int se[BCAP];
    __shared__ int cnt[256];
    __shared__ int cur[256];
    __shared__ int wt[4];
    const int b = blockIdx.x;
    const int t = threadIdx.x;
    const int lane = t & 63;
    const int w = t >> 6;
    const int lo = b * BCAP;
    const int ne = bcnt[b];

    cnt[t] = 0;
    __syncthreads();

    for (int i = t; i < ne; i += 256) {
        const int k = ebuf[lo + i];
        atomicAdd(&cnt[k & 255], 1);
        se[i] = k;
    }
    __syncthreads();

    const int v = cnt[t];
    int s = v;
    #pragma unroll
    for (int off = 1; off < 64; off <<= 1) {
        const int u = __shfl_up(s, off);
        if (lane >= off) s += u;
    }
    if (lane == 63) wt[w] = s;
    __syncthreads();
    int base = 0;
    #pragma unroll
    for (int i = 0; i < 4; ++i)
        if (i < w) base += wt[i];
    const int excl = base + s - v;
    cur[t] = excl;
    const int node = b * 256 + t;
    if (node < N_NODES) {
        offs[node] = lo + excl;
        oend[node] = lo + excl + v;
    }
    __syncthreads();

    for (int i = t; i < ne; i += 256) {
        const int k = se[i];
        const int p = atomicAdd(&cur[k & 255], 1);
        ebuf[lo + p] = k >> 8;
    }
}

// ---------------- edge softmax + aggregate: one wave per dst node ----------------
// 16 lanes per edge (uint2 = 4 bf16/lane): 4 edges per load instruction.
__global__ __launch_bounds__(256) void aggregate(const int* __restrict__ offs,
                                                 const int* __restrict__ oend,
                                                 const int* __restrict__ esrc,
                                                 const float* __restrict__ el,
                                                 const float* __restrict__ er,
                                                 const unsigned short* __restrict__ zb,
                                                 float* __restrict__ out) {
    const int wave = (int)((blockIdx.x * 256 + threadIdx.x) >> 6);
    const int lane = threadIdx.x & 63;
    if (wave >= N_NODES) return;
    const int d = wave;
    const int start = offs[d];
    const int end   = oend[d];
    const int ne    = end - start;
    const float erd = er[d];
    const int q   = lane >> 4;    // edge slot within group of 4
    const int dp8 = lane & 15;    // dim quad: dims [dp8*4, dp8*4+4)

    float a0 = 0.f, a1 = 0.f, a2 = 0.f, a3 = 0.f;
    float dsum = 0.f;

    if (ne <= 64) {
        int s_i = 0;
        float eraw = -INFINITY;
        if (lane < ne) {
            s_i = esrc[start + lane];
            float e = el[s_i] + erd;
            eraw = e > 0.f ? e : NEG_SLOPE * e;
        }
        float m = eraw;
        #pragma unroll
        for (int off = 32; off; off >>= 1) m = fmaxf(m, __shfl_xor(m, off));
        float ex_i = (lane < ne) ? __expf(eraw - m) : 0.f;
        dsum = ex_i;
        #pragma unroll
        for (int off = 32; off; off >>= 1) dsum += __shfl_xor(dsum, off);

        for (int bb = 0; bb < ne; bb += 4) {
            const int idx = bb + q;
            const int cidx = min(idx, ne - 1);
            float wv = __shfl(ex_i, cidx);
            const int sv = __shfl(s_i, cidx);
            if (idx < ne && wv > 0.f) {
                const uint2 zz = *(const uint2*)&zb[((size_t)sv << 6) + (dp8 << 2)];
                a0 += wv * bflo(zz.x); a1 += wv * bfhi(zz.x);
                a2 += wv * bflo(zz.y); a3 += wv * bfhi(zz.y);
            }
        }
    } else {
        float m = -INFINITY;
        for (int i = start + lane; i < end; i += 64) {
            const int s = esrc[i];
            float e = el[s] + erd;
            e = e > 0.f ? e : NEG_SLOPE * e;
            m = fmaxf(m, e);
        }
        #pragma unroll
        for (int off = 32; off; off >>= 1) m = fmaxf(m, __shfl_xor(m, off));

        for (int base = start; base < end; base += 64) {
            const int cl = min(64, end - base);
            int s_i = 0;
            float ex_i = 0.f;
            if (lane < cl) {
                s_i = esrc[base + lane];
                float e = el[s_i] + erd;
                e = e > 0.f ? e : NEG_SLOPE * e;
                ex_i = __expf(e - m);
            }
            dsum += ex_i;
            for (int bb = 0; bb < cl; bb += 4) {
                const int idx = bb + q;
                const int cidx = min(idx, cl - 1);
                float wv = __shfl(ex_i, cidx);
                const int sv = __shfl(s_i, cidx);
                if (idx < cl && wv > 0.f) {
                    const uint2 zz = *(const uint2*)&zb[((size_t)sv << 6) + (dp8 << 2)];
                    a0 += wv * bflo(zz.x); a1 += wv * bfhi(zz.x);
                    a2 += wv * bflo(zz.y); a3 += wv * bfhi(zz.y);
                }
            }
        }
        #pragma unroll
        for (int off = 32; off; off >>= 1) dsum += __shfl_xor(dsum, off);
    }

    // combine across the 4 edge-slots (same dims live at lane, lane^16, lane^32, lane^48)
    a0 += __shfl_xor(a0, 16); a1 += __shfl_xor(a1, 16);
    a2 += __shfl_xor(a2, 16); a3 += __shfl_xor(a3, 16);
    a0 += __shfl_xor(a0, 32); a1 += __shfl_xor(a1, 32);
    a2 += __shfl_xor(a2, 32); a3 += __shfl_xor(a3, 32);

    if (q == 0) {
        const float inv = (ne > 0) ? (1.f / dsum) : 0.f;
        float4 o = {a0 * inv, a1 * inv, a2 * inv, a3 * inv};
        *(float4*)&out[((size_t)d << 6) + (dp8 << 2)] = o;
    }
}

// ---------------- launch ----------------
extern "C" void kernel_launch(void* const* d_in, const int* in_sizes, int n_in,
                              void* d_out, int out_size, void* d_ws, size_t ws_size,
                              hipStream_t stream) {
    const float* h   = (const float*)d_in[0];
    const float* pos = (const float*)d_in[1];
    const int* src   = (const int*)d_in[2];
    const int* dst   = (const int*)d_in[3];
    const float* Wfc = (const float*)d_in[4];
    const float* Wa  = (const float*)d_in[5];
    float* out = (float*)d_out;

    char* ws = (char*)d_ws;
    unsigned short* zb = (unsigned short*)(ws);     // 10,240,000 B
    float* el     = (float*)(ws + 10240000);        // 320,000 B
    float* er     = (float*)(ws + 10560000);        // 320,000 B
    int*   offs   = (int*)  (ws + 10880000);        // 320,000 B
    int*   oend   = (int*)  (ws + 11200000);        // 320,000 B
    int*   ebuf   = (int*)  (ws + 11520000);        // 313*8192*4 = 10,256,384 B
    int*   bcnt   = (int*)  (ws + 21776384);        // 1,252 B

    hipMemsetAsync(bcnt, 0, NB_BUCKET * sizeof(int), stream);
    gemm_scatter<<<GEMM_NB + SCAT_NB, 256, 0, stream>>>(h, Wfc, pos, Wa, src, dst,
                                                        zb, el, er, bcnt, ebuf);
    bucket_csr<<<NB_BUCKET, 256, 0, stream>>>(ebuf, bcnt, offs, oend);
    aggregate<<<N_NODES / 4, 256, 0, stream>>>(offs, oend, ebuf, el, er, zb, out);
}